// Round 2
// baseline (911.934 us; speedup 1.0000x reference)
//
#include <hip/hip_runtime.h>
#include <hip/hip_bf16.h>

typedef __hip_bfloat16 bf16;

#define B_ 16
#define C_ 256
#define H_ 48
#define W_ 48
#define HW_ 2304
#define KK_ 49

// workspace layout (floats)
#define WS_FLAG 0
#define WS_Z 16
#define WS_FS 4112
#define WS_BASIS 40976
#define WS_KBUF 42944

__device__ __forceinline__ float ldf(const void* p, int idx, int isbf) {
  if (isbf) return __bfloat162float(((const bf16*)p)[idx]);
  return ((const float*)p)[idx];
}

__device__ __forceinline__ unsigned pack2(float a, float b) {
  bf16 x = __float2bfloat16(a);
  bf16 y = __float2bfloat16(b);
  unsigned short ux = *reinterpret_cast<unsigned short*>(&x);
  unsigned short uy = *reinterpret_cast<unsigned short*>(&y);
  return (unsigned)ux | ((unsigned)uy << 16);
}

// ---------- K0: dtype detector (f32 vs bf16), graph-safe, deterministic ----------
__global__ void detect_kernel(const unsigned short* __restrict__ raw,
                              int* __restrict__ flag) {
  if (threadIdx.x == 0) {
    int cnt = 0;
    for (int i = 0; i < 256; ++i) {
      unsigned e = ((unsigned)raw[i] >> 7) & 0xFFu;
      if (e >= 0xC8u) ++cnt;  // |x| >= 2^73 impossible for bf16 of N(0,1) data
    }
    *flag = (cnt >= 4) ? 0 : 1;  // 0 = f32, 1 = bf16
  }
}

// ---------- K1: z[b,c] = mean over H*W ----------
__global__ __launch_bounds__(256) void z_kernel(const void* __restrict__ feat,
                                                float* __restrict__ z,
                                                const int* __restrict__ flag) {
  int isbf = *flag;
  int plane = blockIdx.x;  // b*C + c, 4096 planes
  float acc = 0.f;
  if (isbf) {
    const unsigned* fp =
        reinterpret_cast<const unsigned*>(feat) + (size_t)plane * (HW_ / 2);
    for (int i = threadIdx.x; i < HW_ / 2; i += 256) {
      unsigned u = fp[i];
      acc += __uint_as_float(u << 16) + __uint_as_float(u & 0xffff0000u);
    }
  } else {
    const float4* fp =
        reinterpret_cast<const float4*>((const float*)feat + (size_t)plane * HW_);
    for (int i = threadIdx.x; i < HW_ / 4; i += 256) {
      float4 v = fp[i];
      acc += v.x + v.y + v.z + v.w;
    }
  }
#pragma unroll
  for (int off = 32; off; off >>= 1) acc += __shfl_xor(acc, off, 64);
  __shared__ float part[4];
  if ((threadIdx.x & 63) == 0) part[threadIdx.x >> 6] = acc;
  __syncthreads();
  if (threadIdx.x == 0)
    z[plane] = (part[0] + part[1] + part[2] + part[3]) * (1.0f / (float)HW_);
}

// ---------- K2: fs[b,y,x] = sum over channels ----------
__global__ __launch_bounds__(256) void fs_kernel(const void* __restrict__ feat,
                                                 float* __restrict__ fs,
                                                 const int* __restrict__ flag) {
  int isbf = *flag;
  int p = blockIdx.x * 256 + threadIdx.x;  // < B*HW = 36864
  int b = p / HW_;
  int pos = p - b * HW_;
  float acc = 0.f;
  if (isbf) {
    const bf16* f = (const bf16*)feat + (size_t)b * C_ * HW_ + pos;
#pragma unroll 8
    for (int c = 0; c < C_; ++c) acc += __bfloat162float(f[c * HW_]);
  } else {
    const float* f = (const float*)feat + (size_t)b * C_ * HW_ + pos;
#pragma unroll 8
    for (int c = 0; c < C_; ++c) acc += f[c * HW_];
  }
  fs[p] = acc;
}

// ---------- K3: bases (8 inv + 16 eq gaussian, 16 cp harmonic) ----------
__global__ __launch_bounds__(64) void bases_kernel(
    const void* __restrict__ rw1, const void* __restrict__ rb1,
    const void* __restrict__ rw2, const void* __restrict__ rb2,
    float* __restrict__ basis, const int* __restrict__ flag) {
  int isbf = *flag;
  int t = threadIdx.x;
  __shared__ float psi[49];
  __shared__ float nrm;
  float r = 0.f, th = 0.f;
  if (t < 49) {
    int iy = t / 7, ix = t - iy * 7;
    float gy = (float)iy - 3.f, gx = (float)ix - 3.f;
    r = sqrtf(gx * gx + gy * gy + 1e-8f);
    th = atan2f(gy, gx);
  }
  const float SIGL[3] = {4.f, 6.f, 8.f};
  const float SIGS[3] = {1.f, 2.f, 3.f};
  for (int f = 0; f < 24; ++f) {
    int i = (f < 8) ? f : (f - 8);
    int c = i % 9;
    int d = c / 3;
    float s = (f < 8) ? SIGL[c % 3] : SIGS[c % 3];
    float p = 0.f;
    if (t < 49) {
      float u = r / s;
      float g = expf(-0.5f * u * u);
      float pv = (d == 0) ? 1.0f : ((d == 1) ? u : (u * u - 1.0f));
      p = pv * g;
      psi[t] = p;
    }
    __syncthreads();
    if (t == 0) {
      float ss = 0.f;
      for (int q = 0; q < 49; ++q) ss += psi[q] * psi[q];
      nrm = sqrtf(ss + 1e-8f);
    }
    __syncthreads();
    if (t < 49) basis[f * 49 + t] = p / nrm;
    __syncthreads();
  }
  if (t < 49) {
    float r0 = ldf(rb2, 0, isbf), r1 = ldf(rb2, 1, isbf);
    for (int j = 0; j < 32; ++j) {
      float h = tanhf(r * ldf(rw1, j, isbf) + ldf(rb1, j, isbf));
      r0 += h * ldf(rw2, 2 * j, isbf);
      r1 += h * ldf(rw2, 2 * j + 1, isbf);
    }
    for (int i = 0; i < 16; ++i) {
      int m = i >> 3, a = i & 7;
      int o = (a >> 1) + 1;
      float ang = (a & 1) ? sinf((float)o * th) : cosf((float)o * th);
      basis[(24 + i) * 49 + t] = (m ? r1 : r0) * ang;
    }
  }
}

// ---------- K4: coeff MLPs + per-sample 7x7 kernels ----------
template <int N>
__device__ __forceinline__ void do_branch(
    int b, int c, int isbf, const float* __restrict__ zs, float* hs, float* bs,
    const void* __restrict__ w1, const void* __restrict__ b1,
    const void* __restrict__ w2, const void* __restrict__ b2,
    const float* __restrict__ basis, float* __restrict__ kb_out) {
  if (c < 64) {
    float acc = ldf(b1, c, isbf);
    for (int q = 0; q < 256; ++q) acc = fmaf(zs[q], ldf(w1, q * 64 + c, isbf), acc);
    hs[c] = fmaxf(acc, 0.0f);
  }
  for (int idx = c; idx < N * 49; idx += 256) bs[idx] = basis[idx];
  __syncthreads();
  float coeff[N];
#pragma unroll
  for (int ni = 0; ni < N; ++ni) {
    float acc = ldf(b2, ni * 256 + c, isbf);
    for (int j = 0; j < 64; ++j)
      acc = fmaf(hs[j], ldf(w2, j * (N * 256) + ni * 256 + c, isbf), acc);
    coeff[ni] = acc;
  }
#pragma unroll 7
  for (int t = 0; t < 49; ++t) {
    float kt = 0.f;
#pragma unroll
    for (int ni = 0; ni < N; ++ni) kt = fmaf(coeff[ni], bs[ni * 49 + t], kt);
    kb_out[t * 256 + c] = kt;
  }
  __syncthreads();
}

__global__ __launch_bounds__(256) void coeff_kernel(
    const float* __restrict__ z, const float* __restrict__ basis,
    float* __restrict__ kbuf, const int* __restrict__ flag, const void* w1i,
    const void* b1i, const void* w2i, const void* b2i, const void* w1e,
    const void* b1e, const void* w2e, const void* b2e, const void* w1c,
    const void* b1c, const void* w2c, const void* b2c) {
  __shared__ float zs[256];
  __shared__ float hs[64];
  __shared__ float bs[16 * 49];
  int isbf = *flag;
  int b = blockIdx.x, c = threadIdx.x;
  zs[c] = z[b * 256 + c];
  __syncthreads();
  do_branch<8>(b, c, isbf, zs, hs, bs, w1i, b1i, w2i, b2i, basis,
               kbuf + 0 * (B_ * KK_ * C_) + b * (KK_ * C_));
  do_branch<16>(b, c, isbf, zs, hs, bs, w1e, b1e, w2e, b2e, basis + 8 * 49,
                kbuf + 1 * (B_ * KK_ * C_) + b * (KK_ * C_));
  do_branch<16>(b, c, isbf, zs, hs, bs, w1c, b1c, w2c, b2c, basis + 24 * 49,
                kbuf + 2 * (B_ * KK_ * C_) + b * (KK_ * C_));
}

// ---------- K5: per-sample conv (cross-correlation, SAME pad) + channel-LN ----------
__global__ __launch_bounds__(256) void conv_ln_kernel(
    const float* __restrict__ fs, const float* __restrict__ kbuf,
    const int* __restrict__ flag, const void* __restrict__ g0,
    const void* __restrict__ be0, const void* __restrict__ g1,
    const void* __restrict__ be1, const void* __restrict__ g2,
    const void* __restrict__ be2, void* __restrict__ out) {
  int isbf = *flag;
  int bid = blockIdx.x;
  int branch = bid / (B_ * H_);
  int rem = bid - branch * (B_ * H_);
  int b = rem / H_;
  int y = rem - b * H_;
  int tid = threadIdx.x;

  __shared__ float srow[7 * 56];  // 7 rows, 48 cols + 3 pad each side
  __shared__ float red[4][96];
  __shared__ float stats[96];  // mu[0..47], rstd[48..95]

  for (int idx = tid; idx < 7 * 56; idx += 256) {
    int dy = idx / 56, col = idx - dy * 56;
    int gy = y + dy - 3, gx = col - 3;
    float v = 0.f;
    if (gy >= 0 && gy < H_ && gx >= 0 && gx < W_) v = fs[b * HW_ + gy * W_ + gx];
    srow[idx] = v;
  }

  float kreg[49];
  const float* kb =
      kbuf + (size_t)branch * (B_ * KK_ * C_) + b * (KK_ * C_) + tid;
#pragma unroll
  for (int t = 0; t < 49; ++t) kreg[t] = kb[t * 256];

  __syncthreads();

  float val[48];
#pragma unroll
  for (int x = 0; x < 48; ++x) val[x] = 0.f;

#pragma unroll
  for (int dy = 0; dy < 7; ++dy) {
#pragma unroll
    for (int i = 0; i < 54; ++i) {
      float rv = srow[dy * 56 + i];
#pragma unroll
      for (int dx = 0; dx < 7; ++dx) {
        int x = i - dx;
        if (x >= 0 && x < 48) val[x] = fmaf(rv, kreg[dy * 7 + dx], val[x]);
      }
    }
  }

  int lane = tid & 63, w = tid >> 6;
#pragma unroll
  for (int x = 0; x < 48; ++x) {
    float s = val[x];
    float q = s * s;
#pragma unroll
    for (int off = 32; off; off >>= 1) {
      s += __shfl_xor(s, off, 64);
      q += __shfl_xor(q, off, 64);
    }
    if (lane == 0) {
      red[w][x] = s;
      red[w][48 + x] = q;
    }
  }
  __syncthreads();
  if (tid < 48) {
    float s = red[0][tid] + red[1][tid] + red[2][tid] + red[3][tid];
    float q = red[0][48 + tid] + red[1][48 + tid] + red[2][48 + tid] +
              red[3][48 + tid];
    float mu = s * (1.f / 256.f);
    float var = q * (1.f / 256.f) - mu * mu;
    stats[tid] = mu;
    stats[48 + tid] = rsqrtf(var + 1e-5f);
  }
  __syncthreads();

  const void* gp = (branch == 0) ? g0 : ((branch == 1) ? g1 : g2);
  const void* bp = (branch == 0) ? be0 : ((branch == 1) ? be1 : be2);
  float g = ldf(gp, tid, isbf), bb = ldf(bp, tid, isbf);

#pragma unroll
  for (int x = 0; x < 48; ++x)
    val[x] = (val[x] - stats[x]) * stats[48 + x] * g + bb;

  size_t obase = (size_t)branch * (B_ * C_ * HW_) +
                 ((size_t)(b * C_ + tid) * H_ + y) * W_;
  if (isbf) {
    unsigned ou[24];
#pragma unroll
    for (int x = 0; x < 48; x += 2) ou[x >> 1] = pack2(val[x], val[x + 1]);
    uint4* o4 = reinterpret_cast<uint4*>((bf16*)out + obase);
    const uint4* s4 = reinterpret_cast<const uint4*>(ou);
#pragma unroll
    for (int i = 0; i < 6; ++i) o4[i] = s4[i];
  } else {
    float4* o4 = reinterpret_cast<float4*>((float*)out + obase);
    const float4* s4 = reinterpret_cast<const float4*>(val);
#pragma unroll
    for (int i = 0; i < 12; ++i) o4[i] = s4[i];
  }
}

extern "C" void kernel_launch(void* const* d_in, const int* in_sizes, int n_in,
                              void* d_out, int out_size, void* d_ws,
                              size_t ws_size, hipStream_t stream) {
  const void* feat = d_in[0];
  float* ws = (float*)d_ws;
  int* flag = (int*)(ws + WS_FLAG);
  float* z = ws + WS_Z;
  float* fs = ws + WS_FS;
  float* basis = ws + WS_BASIS;
  float* kbuf = ws + WS_KBUF;

  detect_kernel<<<1, 64, 0, stream>>>((const unsigned short*)feat, flag);
  z_kernel<<<B_ * C_, 256, 0, stream>>>(feat, z, flag);
  fs_kernel<<<(B_ * HW_) / 256, 256, 0, stream>>>(feat, fs, flag);
  bases_kernel<<<1, 64, 0, stream>>>(d_in[13], d_in[14], d_in[15], d_in[16],
                                     basis, flag);
  coeff_kernel<<<B_, 256, 0, stream>>>(z, basis, kbuf, flag, d_in[1], d_in[2],
                                       d_in[3], d_in[4], d_in[5], d_in[6],
                                       d_in[7], d_in[8], d_in[9], d_in[10],
                                       d_in[11], d_in[12]);
  conv_ln_kernel<<<3 * B_ * H_, 256, 0, stream>>>(
      fs, kbuf, flag, d_in[17], d_in[18], d_in[19], d_in[20], d_in[21],
      d_in[22], d_out);
}

// Round 3
// 498.882 us; speedup vs baseline: 1.8280x; 1.8280x over previous
//
#include <hip/hip_runtime.h>
#include <hip/hip_bf16.h>

#define B_ 16
#define C_ 256
#define H_ 48
#define W_ 48
#define HW_ 2304
#define KK_ 49

// workspace layout (floats)
#define WS_Z 16
#define WS_FS 4112
#define WS_BASIS 40976
#define WS_KBUF 42944

// ---------- K1: z[b,c] = mean over H*W ----------
__global__ __launch_bounds__(256) void z_kernel(const float* __restrict__ feat,
                                                float* __restrict__ z) {
  int plane = blockIdx.x;  // b*C + c, 4096 planes
  const float4* fp =
      reinterpret_cast<const float4*>(feat + (size_t)plane * HW_);
  float acc = 0.f;
  for (int i = threadIdx.x; i < HW_ / 4; i += 256) {
    float4 v = fp[i];
    acc += v.x + v.y + v.z + v.w;
  }
#pragma unroll
  for (int off = 32; off; off >>= 1) acc += __shfl_xor(acc, off, 64);
  __shared__ float part[4];
  if ((threadIdx.x & 63) == 0) part[threadIdx.x >> 6] = acc;
  __syncthreads();
  if (threadIdx.x == 0)
    z[plane] = (part[0] + part[1] + part[2] + part[3]) * (1.0f / (float)HW_);
}

// ---------- K2: fs[b,y,x] = sum over channels ----------
__global__ __launch_bounds__(256) void fs_kernel(const float* __restrict__ feat,
                                                 float* __restrict__ fs) {
  int p = blockIdx.x * 256 + threadIdx.x;  // < B*HW = 36864
  int b = p / HW_;
  int pos = p - b * HW_;
  const float* f = feat + (size_t)b * C_ * HW_ + pos;
  float acc = 0.f;
#pragma unroll 8
  for (int c = 0; c < C_; ++c) acc += f[c * HW_];
  fs[p] = acc;
}

// ---------- K3: bases (8 inv + 16 eq gaussian, 16 cp harmonic) ----------
__global__ __launch_bounds__(64) void bases_kernel(
    const float* __restrict__ rw1, const float* __restrict__ rb1,
    const float* __restrict__ rw2, const float* __restrict__ rb2,
    float* __restrict__ basis) {
  int t = threadIdx.x;
  __shared__ float psi[49];
  __shared__ float nrm;
  float r = 0.f, th = 0.f;
  if (t < 49) {
    int iy = t / 7, ix = t - iy * 7;
    float gy = (float)iy - 3.f, gx = (float)ix - 3.f;
    r = sqrtf(gx * gx + gy * gy + 1e-8f);
    th = atan2f(gy, gx);
  }
  const float SIGL[3] = {4.f, 6.f, 8.f};
  const float SIGS[3] = {1.f, 2.f, 3.f};
  for (int f = 0; f < 24; ++f) {
    int i = (f < 8) ? f : (f - 8);
    int c = i % 9;
    int d = c / 3;
    float s = (f < 8) ? SIGL[c % 3] : SIGS[c % 3];
    float p = 0.f;
    if (t < 49) {
      float u = r / s;
      float g = expf(-0.5f * u * u);
      float pv = (d == 0) ? 1.0f : ((d == 1) ? u : (u * u - 1.0f));
      p = pv * g;
      psi[t] = p;
    }
    __syncthreads();
    if (t == 0) {
      float ss = 0.f;
      for (int q = 0; q < 49; ++q) ss += psi[q] * psi[q];
      nrm = sqrtf(ss + 1e-8f);
    }
    __syncthreads();
    if (t < 49) basis[f * 49 + t] = p / nrm;
    __syncthreads();
  }
  if (t < 49) {
    float r0 = rb2[0], r1 = rb2[1];
    for (int j = 0; j < 32; ++j) {
      float h = tanhf(r * rw1[j] + rb1[j]);
      r0 += h * rw2[2 * j];
      r1 += h * rw2[2 * j + 1];
    }
    for (int i = 0; i < 16; ++i) {
      int m = i >> 3, a = i & 7;
      int o = (a >> 1) + 1;
      float ang = (a & 1) ? sinf((float)o * th) : cosf((float)o * th);
      basis[(24 + i) * 49 + t] = (m ? r1 : r0) * ang;
    }
  }
}

// ---------- K4: coeff MLP + per-sample 7x7 kernels (one branch per launch) ----------
// grid = 16 (one block per sample), 256 threads (one per output channel)
template <int N>
__global__ __launch_bounds__(256) void coeff_kernel(
    const float* __restrict__ z, const float* __restrict__ basis,
    const float* __restrict__ w1, const float* __restrict__ b1,
    const float* __restrict__ w2, const float* __restrict__ b2,
    float* __restrict__ kbuf) {
  int b = blockIdx.x, c = threadIdx.x;
  __shared__ float zs[256];
  __shared__ float hp[4][64];
  __shared__ float hs[64];
  __shared__ float bs[16 * 49];
  zs[c] = z[b * 256 + c];
  for (int i = c; i < N * 49; i += 256) bs[i] = basis[i];
  __syncthreads();
  // h = relu(z @ w1 + b1): 4 partial threads per hidden unit
  {
    int j = c & 63, part = c >> 6;
    float acc = 0.f;
    const float* w1p = w1 + (part * 64) * 64 + j;
#pragma unroll 8
    for (int q = 0; q < 64; ++q) acc = fmaf(zs[part * 64 + q], w1p[q * 64], acc);
    hp[part][j] = acc;
  }
  __syncthreads();
  if (c < 64)
    hs[c] = fmaxf(b1[c] + hp[0][c] + hp[1][c] + hp[2][c] + hp[3][c], 0.f);
  __syncthreads();
  // coeff[n] = b2 + h @ w2 column   (coalesced f32 loads, fully pipelined)
  float coeff[N];
#pragma unroll
  for (int n = 0; n < N; ++n) coeff[n] = b2[n * 256 + c];
#pragma unroll 4
  for (int j = 0; j < 64; ++j) {
    float h = hs[j];
    const float* wrow = w2 + (size_t)j * (N * 256) + c;
#pragma unroll
    for (int n = 0; n < N; ++n) coeff[n] = fmaf(h, wrow[n * 256], coeff[n]);
  }
  // k[t] = sum_n coeff[n] * basis[n][t]
  float* ko = kbuf + (size_t)b * (KK_ * C_) + c;
#pragma unroll 7
  for (int t = 0; t < 49; ++t) {
    float kt = 0.f;
#pragma unroll
    for (int n = 0; n < N; ++n) kt = fmaf(coeff[n], bs[n * 49 + t], kt);
    ko[t * 256] = kt;
  }
}

// ---------- K5: per-sample conv (cross-correlation, SAME pad) + channel-LN ----------
__global__ __launch_bounds__(256) void conv_ln_kernel(
    const float* __restrict__ fs, const float* __restrict__ kbuf,
    const float* __restrict__ g0, const float* __restrict__ be0,
    const float* __restrict__ g1, const float* __restrict__ be1,
    const float* __restrict__ g2, const float* __restrict__ be2,
    float* __restrict__ out) {
  int bid = blockIdx.x;
  int branch = bid / (B_ * H_);
  int rem = bid - branch * (B_ * H_);
  int b = rem / H_;
  int y = rem - b * H_;
  int tid = threadIdx.x;

  __shared__ float srow[7 * 56];  // 7 rows, 48 cols + 3 pad each side (16B-aligned rows)
  __shared__ float red[4][96];
  __shared__ float stats[96];  // mu[0..47], rstd[48..95]

  for (int idx = tid; idx < 7 * 56; idx += 256) {
    int dy = idx / 56, col = idx - dy * 56;
    int gy = y + dy - 3, gx = col - 3;
    float v = 0.f;
    if (gy >= 0 && gy < H_ && gx >= 0 && gx < W_) v = fs[b * HW_ + gy * W_ + gx];
    srow[idx] = v;
  }

  float kreg[49];
  const float* kb =
      kbuf + (size_t)branch * (B_ * KK_ * C_) + b * (KK_ * C_) + tid;
#pragma unroll
  for (int t = 0; t < 49; ++t) kreg[t] = kb[t * 256];

  __syncthreads();

  float val[48];
#pragma unroll
  for (int x = 0; x < 48; ++x) val[x] = 0.f;

  // all indices compile-time constant: no conditionals, no dynamic indexing
#pragma unroll
  for (int dy = 0; dy < 7; ++dy) {
    float rr[54];
#pragma unroll
    for (int i = 0; i < 54; ++i) rr[i] = srow[dy * 56 + i];
#pragma unroll
    for (int dx = 0; dx < 7; ++dx) {
      float kv = kreg[dy * 7 + dx];
#pragma unroll
      for (int x = 0; x < 48; ++x) val[x] = fmaf(rr[x + dx], kv, val[x]);
    }
  }

  int lane = tid & 63, w = tid >> 6;
#pragma unroll
  for (int x = 0; x < 48; ++x) {
    float s = val[x];
    float q = s * s;
#pragma unroll
    for (int off = 32; off; off >>= 1) {
      s += __shfl_xor(s, off, 64);
      q += __shfl_xor(q, off, 64);
    }
    if (lane == 0) {
      red[w][x] = s;
      red[w][48 + x] = q;
    }
  }
  __syncthreads();
  if (tid < 48) {
    float s = red[0][tid] + red[1][tid] + red[2][tid] + red[3][tid];
    float q = red[0][48 + tid] + red[1][48 + tid] + red[2][48 + tid] +
              red[3][48 + tid];
    float mu = s * (1.f / 256.f);
    float var = q * (1.f / 256.f) - mu * mu;
    stats[tid] = mu;
    stats[48 + tid] = rsqrtf(var + 1e-5f);
  }
  __syncthreads();

  const float* gp = (branch == 0) ? g0 : ((branch == 1) ? g1 : g2);
  const float* bp = (branch == 0) ? be0 : ((branch == 1) ? be1 : be2);
  float g = gp[tid], bb = bp[tid];

#pragma unroll
  for (int x = 0; x < 48; ++x)
    val[x] = (val[x] - stats[x]) * stats[48 + x] * g + bb;

  size_t obase = (size_t)branch * (B_ * C_ * HW_) +
                 ((size_t)(b * C_ + tid) * H_ + y) * W_;
  float4* o4 = reinterpret_cast<float4*>(out + obase);
  const float4* s4 = reinterpret_cast<const float4*>(val);
#pragma unroll
  for (int i = 0; i < 12; ++i) o4[i] = s4[i];
}

extern "C" void kernel_launch(void* const* d_in, const int* in_sizes, int n_in,
                              void* d_out, int out_size, void* d_ws,
                              size_t ws_size, hipStream_t stream) {
  const float* feat = (const float*)d_in[0];
  float* ws = (float*)d_ws;
  float* z = ws + WS_Z;
  float* fs = ws + WS_FS;
  float* basis = ws + WS_BASIS;
  float* kbuf = ws + WS_KBUF;

  z_kernel<<<B_ * C_, 256, 0, stream>>>(feat, z);
  fs_kernel<<<(B_ * HW_) / 256, 256, 0, stream>>>(feat, fs);
  bases_kernel<<<1, 64, 0, stream>>>((const float*)d_in[13],
                                     (const float*)d_in[14],
                                     (const float*)d_in[15],
                                     (const float*)d_in[16], basis);
  coeff_kernel<8><<<B_, 256, 0, stream>>>(
      z, basis, (const float*)d_in[1], (const float*)d_in[2],
      (const float*)d_in[3], (const float*)d_in[4], kbuf + 0 * (B_ * KK_ * C_));
  coeff_kernel<16><<<B_, 256, 0, stream>>>(
      z, basis + 8 * 49, (const float*)d_in[5], (const float*)d_in[6],
      (const float*)d_in[7], (const float*)d_in[8], kbuf + 1 * (B_ * KK_ * C_));
  coeff_kernel<16><<<B_, 256, 0, stream>>>(
      z, basis + 24 * 49, (const float*)d_in[9], (const float*)d_in[10],
      (const float*)d_in[11], (const float*)d_in[12],
      kbuf + 2 * (B_ * KK_ * C_));
  conv_ln_kernel<<<3 * B_ * H_, 256, 0, stream>>>(
      fs, kbuf, (const float*)d_in[17], (const float*)d_in[18],
      (const float*)d_in[19], (const float*)d_in[20], (const float*)d_in[21],
      (const float*)d_in[22], (float*)d_out);
}

// Round 4
// 470.106 us; speedup vs baseline: 1.9398x; 1.0612x over previous
//
#include <hip/hip_runtime.h>

#define B_ 16
#define C_ 256
#define H_ 48
#define W_ 48
#define HW_ 2304
#define KK_ 49

// ws offsets in floats
#define WS_ZPART 0          // [16][256][9] = 36864   (dead after reduce2)
#define WS_FSPART 36864     // [4][16*2304] = 147456  (dead after reduce2)
#define WS_COEFF 0          // [16][40][256] = 163840 (reuses zpart/fspart region)
#define WS_Z 184320         // 4096
#define WS_FS 188416        // 36864
#define WS_BASIS 225280     // 40*52 = 2080
#define WS_H 227360         // 3*16*64 = 3072
#define WS_KBUF 230432      // 3*16*257*52 = 641232 -> end 871664 floats (3.49 MB)

__device__ __forceinline__ float wave_sum(float v) {
#pragma unroll
  for (int off = 32; off; off >>= 1) v += __shfl_xor(v, off, 64);
  return v;
}

// ---------- K1: fused single pass over feature: z partials + fs partials ----------
// grid (16 b, 4 c-chunks, 9 pos-chunks), 256 threads
__global__ __launch_bounds__(256) void zfs1_kernel(const float* __restrict__ feat,
                                                   float* __restrict__ zpart,
                                                   float* __restrict__ fspart) {
  int b = blockIdx.x, cc = blockIdx.y, pc = blockIdx.z;
  int tid = threadIdx.x;
  int p = pc * 256 + tid;
  const float* f = feat + ((size_t)b * C_ + cc * 64) * HW_ + p;
  __shared__ float zsum[256];
  int w = tid >> 6, lane = tid & 63;
  float facc = 0.f;
#pragma unroll 8
  for (int j = 0; j < 64; ++j) {
    float v = f[(size_t)j * HW_];
    facc += v;
    float s = wave_sum(v);
    if (lane == 0) zsum[w * 64 + j] = s;
  }
  fspart[cc * (B_ * HW_) + b * HW_ + p] = facc;
  __syncthreads();
  if (tid < 64) {
    float zv = zsum[tid] + zsum[64 + tid] + zsum[128 + tid] + zsum[192 + tid];
    zpart[((size_t)b * 256 + cc * 64 + tid) * 9 + pc] = zv;
  }
}

// ---------- K2: finish z and fs ----------
__global__ __launch_bounds__(256) void reduce2_kernel(
    const float* __restrict__ zpart, const float* __restrict__ fspart,
    float* __restrict__ z, float* __restrict__ fs) {
  int bid = blockIdx.x, tid = threadIdx.x;
  if (bid < 16) {
    const float* zp = zpart + ((size_t)bid * 256 + tid) * 9;
    float s = 0.f;
#pragma unroll
    for (int i = 0; i < 9; ++i) s += zp[i];
    z[bid * 256 + tid] = s * (1.0f / (float)HW_);
  } else {
    int p = (bid - 16) * 256 + tid;
    fs[p] = fspart[p] + fspart[B_ * HW_ + p] + fspart[2 * B_ * HW_ + p] +
            fspart[3 * B_ * HW_ + p];
  }
}

// ---------- K3: bases, padded rows of 52 ----------
__global__ __launch_bounds__(64) void bases_kernel(
    const float* __restrict__ rw1, const float* __restrict__ rb1,
    const float* __restrict__ rw2, const float* __restrict__ rb2,
    float* __restrict__ basis) {
  int t = threadIdx.x;
  float r = 0.f, th = 0.f;
  if (t < 49) {
    int iy = t / 7, ix = t - iy * 7;
    float gy = (float)iy - 3.f, gx = (float)ix - 3.f;
    r = sqrtf(gx * gx + gy * gy + 1e-8f);
    th = atan2f(gy, gx);
  }
  const float SIGL[3] = {4.f, 6.f, 8.f};
  const float SIGS[3] = {1.f, 2.f, 3.f};
#pragma unroll 1
  for (int f = 0; f < 24; ++f) {
    int i = (f < 8) ? f : (f - 8);
    int c = i % 9;
    int d = c / 3;
    float s = (f < 8) ? SIGL[c % 3] : SIGS[c % 3];
    float p = 0.f;
    if (t < 49) {
      float u = r / s;
      float g = expf(-0.5f * u * u);
      p = ((d == 0) ? 1.0f : ((d == 1) ? u : (u * u - 1.0f))) * g;
    }
    float ss = wave_sum(p * p);
    if (t < 49) basis[f * 52 + t] = p / sqrtf(ss + 1e-8f);
  }
  if (t < 49) {
    float r0 = rb2[0], r1 = rb2[1];
    for (int j = 0; j < 32; ++j) {
      float h = tanhf(r * rw1[j] + rb1[j]);
      r0 += h * rw2[2 * j];
      r1 += h * rw2[2 * j + 1];
    }
#pragma unroll
    for (int i = 0; i < 16; ++i) {
      int m = i >> 3, a = i & 7;
      int o = (a >> 1) + 1;
      float ang = (a & 1) ? sinf((float)o * th) : cosf((float)o * th);
      basis[(24 + i) * 52 + t] = (m ? r1 : r0) * ang;
    }
  }
}

// ---------- K4: h = relu(z @ w1 + b1), grid 48 = (branch, b) ----------
__global__ __launch_bounds__(256) void h_kernel(
    const float* __restrict__ z, const float* __restrict__ w1i,
    const float* __restrict__ b1i, const float* __restrict__ w1e,
    const float* __restrict__ b1e, const float* __restrict__ w1c,
    const float* __restrict__ b1c, float* __restrict__ hout) {
  int branch = blockIdx.x >> 4, b = blockIdx.x & 15, tid = threadIdx.x;
  const float* w1 = branch == 0 ? w1i : (branch == 1 ? w1e : w1c);
  const float* b1 = branch == 0 ? b1i : (branch == 1 ? b1e : b1c);
  __shared__ float zs[256], hp[256];
  zs[tid] = z[b * 256 + tid];
  __syncthreads();
  int j = tid & 63, part = tid >> 6;
  float acc = 0.f;
  const float* wp = w1 + (part * 64) * 64 + j;
#pragma unroll 8
  for (int q = 0; q < 64; ++q) acc = fmaf(zs[part * 64 + q], wp[q * 64], acc);
  hp[tid] = acc;
  __syncthreads();
  if (tid < 64)
    hout[blockIdx.x * 64 + tid] =
        fmaxf(b1[tid] + hp[tid] + hp[64 + tid] + hp[128 + tid] + hp[192 + tid],
              0.f);
}

// ---------- K5: coeff[b,ng,c] = b2 + h @ w2 col, grid (16, 40) ----------
__global__ __launch_bounds__(256) void coeffA_kernel(
    const float* __restrict__ hbuf, const float* __restrict__ w2i,
    const float* __restrict__ b2i, const float* __restrict__ w2e,
    const float* __restrict__ b2e, const float* __restrict__ w2c,
    const float* __restrict__ b2c, float* __restrict__ coeff) {
  int b = blockIdx.x, ng = blockIdx.y, c = threadIdx.x;
  int branch = (ng < 8) ? 0 : ((ng < 24) ? 1 : 2);
  int nl = ng - ((branch == 0) ? 0 : ((branch == 1) ? 8 : 24));
  int Nc = (branch == 0) ? 8 : 16;
  const float* w2 = branch == 0 ? w2i : (branch == 1 ? w2e : w2c);
  const float* b2 = branch == 0 ? b2i : (branch == 1 ? b2e : b2c);
  __shared__ float hs[64];
  if (c < 64) hs[c] = hbuf[(branch * 16 + b) * 64 + c];
  __syncthreads();
  float acc = b2[nl * 256 + c];
  const float* wp = w2 + (size_t)nl * 256 + c;
  size_t stride = (size_t)Nc * 256;
#pragma unroll 8
  for (int jj = 0; jj < 64; ++jj) acc = fmaf(hs[jj], wp[jj * stride], acc);
  coeff[((size_t)b * 40 + ng) * 256 + c] = acc;
}

// ---------- K6: k[c][t] = sum_n coeff*basis (row-padded 52) + kmean row ----------
template <int N>
__global__ __launch_bounds__(256) void coeffB_kernel(
    const float* __restrict__ coeff, const float* __restrict__ basis,
    float* __restrict__ kbuf, int branch0) {
  int b = blockIdx.x;
  int branch = branch0 + blockIdx.y;
  int ng0 = (branch == 0) ? 0 : ((branch == 1) ? 8 : 24);
  int c = threadIdx.x;
  __shared__ float bs[16 * 52];
  __shared__ float cm[4][16];
  __shared__ float cmean[16];
  for (int idx = c; idx < N * 52; idx += 256) bs[idx] = basis[ng0 * 52 + idx];
  float cf[N];
#pragma unroll
  for (int n = 0; n < N; ++n)
    cf[n] = coeff[((size_t)b * 40 + ng0 + n) * 256 + c];
  int lane = c & 63, w = c >> 6;
#pragma unroll
  for (int n = 0; n < N; ++n) {
    float s = wave_sum(cf[n]);
    if (lane == 0) cm[w][n] = s;
  }
  __syncthreads();  // covers bs load + cm writes
  if (c < N)
    cmean[c] = (cm[0][c] + cm[1][c] + cm[2][c] + cm[3][c]) * (1.f / 256.f);
  __syncthreads();
  float kr[52];
#pragma unroll
  for (int t = 0; t < 52; ++t) kr[t] = 0.f;
#pragma unroll 7
  for (int t = 0; t < 49; ++t) {
    float kt = 0.f;
#pragma unroll
    for (int n = 0; n < N; ++n) kt = fmaf(cf[n], bs[n * 52 + t], kt);
    kr[t] = kt;
  }
  float* ko = kbuf + ((size_t)(branch * 16 + b) * 257 + c) * 52;
#pragma unroll
  for (int i = 0; i < 13; ++i)
    reinterpret_cast<float4*>(ko)[i] = reinterpret_cast<const float4*>(kr)[i];
  if (c < 49) {
    float km = 0.f;
#pragma unroll
    for (int n = 0; n < N; ++n) km = fmaf(cmean[n], bs[n * 52 + c], km);
    kbuf[((size_t)(branch * 16 + b) * 257 + 256) * 52 + c] = km;
  }
}

// ---------- K7: conv + LN, grid 3*16*48*2 (branch,b,y,half), 256 thr ----------
__global__ __launch_bounds__(256) void conv_ln_kernel(
    const float* __restrict__ fs, const float* __restrict__ kbuf,
    const float* __restrict__ g0, const float* __restrict__ be0,
    const float* __restrict__ g1, const float* __restrict__ be1,
    const float* __restrict__ g2, const float* __restrict__ be2,
    float* __restrict__ out) {
  int bid = blockIdx.x;
  int branch = bid / 1536;
  int rr0 = bid - branch * 1536;
  int b = rr0 / 96;
  int r2 = rr0 - b * 96;
  int y = r2 >> 1;
  int half = r2 & 1;
  int x0 = half * 24;
  int tid = threadIdx.x;

  __shared__ float srow[7 * 32];  // cols j: gx = x0 - 3 + j, j < 30 valid
  __shared__ __align__(16) float kms[52];
  __shared__ float red[4][24];
  __shared__ float stats[48];  // mu[0..23], rstd[24..47]

  if (tid < 224) {
    int dy = tid >> 5, j = tid & 31;
    float v = 0.f;
    int gy = y + dy - 3, gx = x0 - 3 + j;
    if (j < 30 && gy >= 0 && gy < H_ && gx >= 0 && gx < W_)
      v = fs[b * HW_ + gy * W_ + gx];
    srow[tid] = v;
  } else if (tid < 237) {
    int i = tid - 224;
    reinterpret_cast<float4*>(kms)[i] = reinterpret_cast<const float4*>(
        kbuf + ((size_t)(branch * 16 + b) * 257 + 256) * 52)[i];
  }

  float kreg[52];
  {
    const float4* kr4 = reinterpret_cast<const float4*>(
        kbuf + ((size_t)(branch * 16 + b) * 257 + tid) * 52);
#pragma unroll
    for (int i = 0; i < 13; ++i)
      reinterpret_cast<float4*>(kreg)[i] = kr4[i];
  }
  __syncthreads();

  float val[24];
#pragma unroll
  for (int x = 0; x < 24; ++x) val[x] = 0.f;

#pragma unroll
  for (int dy = 0; dy < 7; ++dy) {
    float rr[30];
#pragma unroll
    for (int i = 0; i < 30; ++i) rr[i] = srow[dy * 32 + i];
#pragma unroll
    for (int dx = 0; dx < 7; ++dx) {
      float kv = kreg[dy * 7 + dx];
#pragma unroll
      for (int x = 0; x < 24; ++x) val[x] = fmaf(rr[x + dx], kv, val[x]);
    }
  }

  int lane = tid & 63, w = tid >> 6;
#pragma unroll
  for (int x = 0; x < 24; ++x) {
    float q = val[x] * val[x];
#pragma unroll
    for (int off = 32; off; off >>= 1) q += __shfl_xor(q, off, 64);
    if (lane == 0) red[w][x] = q;
  }
  if (tid < 24) {  // mu via kmean (linear in kernel)
    float m = 0.f;
#pragma unroll
    for (int dy = 0; dy < 7; ++dy)
#pragma unroll
      for (int dx = 0; dx < 7; ++dx)
        m = fmaf(kms[dy * 7 + dx], srow[dy * 32 + tid + dx], m);
    stats[tid] = m;
  }
  __syncthreads();
  if (tid < 24) {
    float qs = red[0][tid] + red[1][tid] + red[2][tid] + red[3][tid];
    float mu = stats[tid];
    float var = qs * (1.f / 256.f) - mu * mu;
    stats[24 + tid] = rsqrtf(var + 1e-5f);
  }
  __syncthreads();

  const float* gp = (branch == 0) ? g0 : ((branch == 1) ? g1 : g2);
  const float* bp = (branch == 0) ? be0 : ((branch == 1) ? be1 : be2);
  float g = gp[tid], bb = bp[tid];

#pragma unroll
  for (int x = 0; x < 24; ++x)
    val[x] = (val[x] - stats[x]) * stats[24 + x] * g + bb;

  float* op = out + (size_t)branch * (B_ * C_ * HW_) +
              ((size_t)(b * C_ + tid) * H_ + y) * W_ + x0;
#pragma unroll
  for (int i = 0; i < 6; ++i)
    reinterpret_cast<float4*>(op)[i] = reinterpret_cast<const float4*>(val)[i];
}

extern "C" void kernel_launch(void* const* d_in, const int* in_sizes, int n_in,
                              void* d_out, int out_size, void* d_ws,
                              size_t ws_size, hipStream_t stream) {
  const float* feat = (const float*)d_in[0];
  float* ws = (float*)d_ws;
  float* zpart = ws + WS_ZPART;
  float* fspart = ws + WS_FSPART;
  float* coeff = ws + WS_COEFF;
  float* z = ws + WS_Z;
  float* fs = ws + WS_FS;
  float* basis = ws + WS_BASIS;
  float* hbuf = ws + WS_H;
  float* kbuf = ws + WS_KBUF;

  zfs1_kernel<<<dim3(16, 4, 9), 256, 0, stream>>>(feat, zpart, fspart);
  reduce2_kernel<<<160, 256, 0, stream>>>(zpart, fspart, z, fs);
  bases_kernel<<<1, 64, 0, stream>>>((const float*)d_in[13],
                                     (const float*)d_in[14],
                                     (const float*)d_in[15],
                                     (const float*)d_in[16], basis);
  h_kernel<<<48, 256, 0, stream>>>(z, (const float*)d_in[1],
                                   (const float*)d_in[2],
                                   (const float*)d_in[5],
                                   (const float*)d_in[6],
                                   (const float*)d_in[9],
                                   (const float*)d_in[10], hbuf);
  coeffA_kernel<<<dim3(16, 40), 256, 0, stream>>>(
      hbuf, (const float*)d_in[3], (const float*)d_in[4],
      (const float*)d_in[7], (const float*)d_in[8], (const float*)d_in[11],
      (const float*)d_in[12], coeff);
  coeffB_kernel<8><<<dim3(16, 1), 256, 0, stream>>>(coeff, basis, kbuf, 0);
  coeffB_kernel<16><<<dim3(16, 2), 256, 0, stream>>>(coeff, basis, kbuf, 1);
  conv_ln_kernel<<<4608, 256, 0, stream>>>(
      fs, kbuf, (const float*)d_in[17], (const float*)d_in[18],
      (const float*)d_in[19], (const float*)d_in[20], (const float*)d_in[21],
      (const float*)d_in[22], (float*)d_out);
}